// Round 1
// baseline (93.707 us; speedup 1.0000x reference)
//
#include <hip/hip_runtime.h>
#include <hip/hip_bf16.h>

#define CIN   65
#define COUT  256
#define LIN   577      // (CIN-1)*9 + 1
#define KP    608      // K padded to multiple of 32
#define M_    16384    // B * 64*64
#define N_    1024     // SOUT * COUT

typedef __bf16 bf16x8 __attribute__((ext_vector_type(8)));
typedef float  f32x4  __attribute__((ext_vector_type(4)));

// SIG[r] = flatten(rot90(arange(9).reshape(3,3), r)); SIG[(4-g)&3] = sigma_g^{-1}
__constant__ int SIG[4][9] = {
  {0,1,2,3,4,5,6,7,8},
  {2,5,8,1,4,7,0,3,6},
  {8,7,6,5,4,3,2,1,0},
  {6,3,0,7,4,1,8,5,2}};

// ---------------- kernel 1: rotate + cast weights -> Wg[1024][608] bf16 ----
__global__ void prep_w(const float* __restrict__ W, __hip_bfloat16* __restrict__ Wg) {
  int idx = blockIdx.x * 256 + threadIdx.x;
  if (idx >= N_ * KP) return;
  int f = idx % KP;
  int n = idx / KP;
  int g = n >> 8, o = n & 255;
  float v = 0.f;
  if (f == 0) {
    v = W[o * LIN];
  } else if (f <= 576) {
    int m = (f - 1) >> 6, c1 = (f - 1) & 63;
    int k = SIG[(4 - g) & 3][m];
    v = W[o * LIN + 1 + k * 64 + c1];
  }
  Wg[idx] = __float2bfloat16(v);
}

// ---------------- kernel 2: im2col + t_resc -> A[16384][608] bf16 ----------
__global__ void im2col_k(const float* __restrict__ x, __hip_bfloat16* __restrict__ A) {
  int idx = blockIdx.x * 256 + threadIdx.x;
  if (idx >= M_ * KP) return;
  int f = idx % KP;
  int r = idx / KP;
  int b  = r >> 12, p = r & 4095;
  int py = p >> 6,  px = p & 63;
  const float* xb = x + (size_t)b * (CIN * 4096);
  float v = 0.f;
  if (f == 0) {
    float s = 0.f;
#pragma unroll
    for (int m = 0; m < 9; ++m) {
      int hy = py + m / 3 - 1, wx = px + m % 3 - 1;
      float t = 0.f;
      if (hy >= 0 && hy < 64 && wx >= 0 && wx < 64) t = xb[hy * 64 + wx];
      t = fmaxf(t, 1.f);
      s += t * t;
    }
    v = sqrtf(s - 8.f);
  } else if (f <= 576) {
    int m = (f - 1) >> 6, c = 1 + ((f - 1) & 63);
    int hy = py + m / 3 - 1, wx = px + m % 3 - 1;
    if (hy >= 0 && hy < 64 && wx >= 0 && wx < 64) v = xb[c * 4096 + hy * 64 + wx];
  }
  A[idx] = __float2bfloat16(v);
}

// ---------------- kernel 3: GEMM C[M][N] = A[M][K] * Wg[N][K]^T + bias -----
__device__ __forceinline__ void async_cp16(const void* g, void* lds) {
  __builtin_amdgcn_global_load_lds(
      (const __attribute__((address_space(1))) void*)g,
      (__attribute__((address_space(3))) void*)lds, 16, 0, 0);
}

__global__ __launch_bounds__(256) void gemm_k(const __hip_bfloat16* __restrict__ A,
                                              const __hip_bfloat16* __restrict__ Bw,
                                              const float* __restrict__ bias,
                                              float* __restrict__ out) {
  __shared__ __hip_bfloat16 As[128][32];
  __shared__ __hip_bfloat16 Bs[128][32];
  const int tid  = threadIdx.x;
  const int wave = tid >> 6, lane = tid & 63;
  const int brow = blockIdx.x * 128;
  const int bcol = blockIdx.y * 128;
  const int wr = (wave >> 1) * 64, wc = (wave & 1) * 64;
  const int fr  = lane & 15;
  const int fko = (lane >> 4) * 8;
  f32x4 acc[4][4] = {};

  for (int k0 = 0; k0 < KP; k0 += 32) {
    // stage A,B tiles (128x32 bf16 each) via direct global->LDS, 16B/lane
#pragma unroll
    for (int h = 0; h < 2; ++h) {
      int q   = h * 256 + tid;
      int row = q >> 2, ko = (q & 3) * 8;
      int ldsoff = (h * 256 + wave * 64) * 16;  // wave-uniform base + lane*16
      async_cp16(A  + (size_t)(brow + row) * KP + (k0 + ko), (char*)&As[0][0] + ldsoff);
      async_cp16(Bw + (size_t)(bcol + row) * KP + (k0 + ko), (char*)&Bs[0][0] + ldsoff);
    }
    __syncthreads();  // drains vmcnt -> staged LDS visible

    bf16x8 af[4], bf[4];
#pragma unroll
    for (int i = 0; i < 4; ++i) af[i] = *(const bf16x8*)&As[wr + i * 16 + fr][fko];
#pragma unroll
    for (int j = 0; j < 4; ++j) bf[j] = *(const bf16x8*)&Bs[wc + j * 16 + fr][fko];
#pragma unroll
    for (int i = 0; i < 4; ++i)
#pragma unroll
      for (int j = 0; j < 4; ++j)
        acc[i][j] = __builtin_amdgcn_mfma_f32_16x16x32_bf16(af[i], bf[j], acc[i][j], 0, 0, 0);
    __syncthreads();  // all reads done before next-iter staging overwrites
  }

  // epilogue: C/D layout col=lane&15, row=(lane>>4)*4+reg  [m89-verified]
  const int rbase = (lane >> 4) * 4;
#pragma unroll
  for (int j = 0; j < 4; ++j) {
    int col = bcol + wc + j * 16 + fr;   // n = g*256 + o
    int g = col >> 8, o = col & 255;
    float bv = bias[o];
#pragma unroll
    for (int i = 0; i < 4; ++i) {
#pragma unroll
      for (int r = 0; r < 4; ++r) {
        int row = brow + wr + i * 16 + rbase + r;  // r = b*4096 + p
        int bb = row >> 12, p = row & 4095;
        out[(((size_t)(bb * 4 + g) * 4096 + p) << 8) + o] = acc[i][j][r] + bv;
      }
    }
  }
}

// ---------------- kernel 4: out[...,0] = sqrt(sum_{o>=1} y^2 + 1) ----------
__global__ void fixup_k(float* __restrict__ out) {
  int row  = blockIdx.x * 4 + (threadIdx.x >> 6);
  int lane = threadIdx.x & 63;
  const float4 v = *(const float4*)(out + (size_t)row * 256 + lane * 4);
  float s = v.x * v.x + v.y * v.y + v.z * v.z + v.w * v.w;
  if (lane == 0) s -= v.x * v.x;  // exclude channel 0
#pragma unroll
  for (int d = 1; d < 64; d <<= 1) s += __shfl_xor(s, d);
  if (lane == 0) out[(size_t)row * 256] = sqrtf(s + 1.0f);
}

extern "C" void kernel_launch(void* const* d_in, const int* in_sizes, int n_in,
                              void* d_out, int out_size, void* d_ws, size_t ws_size,
                              hipStream_t stream) {
  const float* x    = (const float*)d_in[0];
  const float* W    = (const float*)d_in[1];
  const float* bias = (const float*)d_in[2];
  float* out = (float*)d_out;

  __hip_bfloat16* Wg = (__hip_bfloat16*)d_ws;                       // 1024*608*2 B
  __hip_bfloat16* A  = (__hip_bfloat16*)((char*)d_ws + (size_t)N_ * KP * 2);  // 16384*608*2 B

  prep_w  <<<(N_ * KP + 255) / 256, 256, 0, stream>>>(W, Wg);
  im2col_k<<<(M_ * KP + 255) / 256, 256, 0, stream>>>(x, A);
  gemm_k  <<<dim3(M_ / 128, N_ / 128), 256, 0, stream>>>(A, Wg, bias, out);
  fixup_k <<<65536 / 4, 256, 0, stream>>>(out);
}

// Round 2
// 69.142 us; speedup vs baseline: 1.3553x; 1.3553x over previous
//
#include <hip/hip_runtime.h>
#include <hip/hip_bf16.h>

#define CIN   65
#define COUT  256
#define LIN   577      // (CIN-1)*9 + 1
#define KP    640      // K padded to multiple of 64
#define M_    16384    // B * 64*64
#define N_    1024     // SOUT * COUT

typedef __bf16 bf16x8 __attribute__((ext_vector_type(8)));
typedef float  f32x4  __attribute__((ext_vector_type(4)));
typedef unsigned short u16x8 __attribute__((ext_vector_type(8)));

// SIG[r] = flatten(rot90(arange(9).reshape(3,3), r)); SIG[(4-g)&3] = sigma_g^{-1}
__constant__ int SIG[4][9] = {
  {0,1,2,3,4,5,6,7,8},
  {2,5,8,1,4,7,0,3,6},
  {8,7,6,5,4,3,2,1,0},
  {6,3,0,7,4,1,8,5,2}};

// ---------------- kernel 1: rotate + cast weights -> Wg[1024][640] bf16 ----
__global__ void prep_w(const float* __restrict__ W, __hip_bfloat16* __restrict__ Wg) {
  int idx = blockIdx.x * 256 + threadIdx.x;
  if (idx >= N_ * KP) return;
  int f = idx % KP;
  int n = idx / KP;
  int g = n >> 8, o = n & 255;
  float v = 0.f;
  if (f == 0) {
    v = W[o * LIN];
  } else if (f <= 576) {
    int m = (f - 1) >> 6, c1 = (f - 1) & 63;
    int k = SIG[(4 - g) & 3][m];
    v = W[o * LIN + 1 + k * 64 + c1];
  }
  Wg[idx] = __float2bfloat16(v);
}

// ---------------- kernel 2: im2col + t_resc -> A[16384][640] bf16 ----------
// One block per (b, py). Stage x[b][0:65][py-1:py+2][:] with halo in LDS
// (coalesced float4 loads), then lane=px packs bf16x8 chunks.
__global__ __launch_bounds__(512) void im2col_k(const float* __restrict__ x,
                                                __hip_bfloat16* __restrict__ A) {
  // lds[c][dy][4+px], px in [-1,64] -> slots 3..68; rows padded to 72 floats
  __shared__ float lds[CIN * 3 * 72];
  const int b  = blockIdx.x >> 6;
  const int py = blockIdx.x & 63;
  const int tid = threadIdx.x;
  const float* xb = x + (size_t)b * (CIN * 4096);

  // zero-fill (covers halo cols + out-of-image rows)
  for (int i = tid; i < CIN * 3 * 18; i += 512)
    *(f32x4*)&lds[i * 4] = (f32x4){0.f, 0.f, 0.f, 0.f};
  __syncthreads();

  // interior: 65*3 rows x 16 float4, coalesced
  for (int i = tid; i < CIN * 3 * 16; i += 512) {
    int pair = i >> 4, j = i & 15;
    int c = pair / 3, dy = pair - c * 3;
    int hy = py + dy - 1;
    if (hy >= 0 && hy < 64) {
      f32x4 v = *(const f32x4*)(xb + c * 4096 + hy * 64 + j * 4);
      *(f32x4*)&lds[c * 216 + dy * 72 + 4 + j * 4] = v;
    }
  }
  __syncthreads();

  const int wave = tid >> 6, px = tid & 63;
  const size_t rowbase = ((size_t)b * 4096 + py * 64 + px) * KP;
  for (int q = wave * 10; q < wave * 10 + 10; ++q) {
    u16x8 pk;
#pragma unroll
    for (int e = 0; e < 8; ++e) {
      int f = q * 8 + e;
      float v;
      if (f == 0) {
        float s = 0.f;
#pragma unroll
        for (int m = 0; m < 9; ++m) {
          float t = fmaxf(lds[(m / 3) * 72 + 3 + px + (m % 3)], 1.f);
          s += t * t;
        }
        v = sqrtf(s - 8.f);
      } else if (f <= 576) {
        int m = (f - 1) >> 6, c = 1 + ((f - 1) & 63);
        v = lds[c * 216 + (m / 3) * 72 + 3 + px + (m % 3)];
      } else {
        v = 0.f;
      }
      union { __hip_bfloat16 h; unsigned short u; } cv;
      cv.h = __float2bfloat16(v);
      pk[e] = cv.u;
    }
    *(u16x8*)(A + rowbase + q * 8) = pk;
  }
}

// ---------------- kernel 3: GEMM C[M][N] = A[M][K] * Wg[N][K]^T + bias -----
__device__ __forceinline__ void async_cp16(const void* g, void* ldsbase) {
  __builtin_amdgcn_global_load_lds(
      (const __attribute__((address_space(1))) void*)g,
      (__attribute__((address_space(3))) void*)ldsbase, 16, 0, 0);
}

// Tiles 128x128, BK=64. LDS linear [row][chunk] with XOR swizzle:
// physical 16B-chunk p at row r holds logical chunk p^(r&7). Applied by
// pre-swizzling the GLOBAL source column (global_load_lds dest is linear,
// wave-uniform base + lane*16) and XOR-ing the ds_read address.
__global__ __launch_bounds__(256) void gemm_k(const __hip_bfloat16* __restrict__ A,
                                              const __hip_bfloat16* __restrict__ Bw,
                                              const float* __restrict__ bias,
                                              float* __restrict__ out) {
  __shared__ __hip_bfloat16 As[128 * 64];
  __shared__ __hip_bfloat16 Bs[128 * 64];
  const int tid  = threadIdx.x;
  const int wave = tid >> 6, lane = tid & 63;
  const int brow = blockIdx.x * 128;
  const int bcol = blockIdx.y * 128;
  const int wr = (wave >> 1) * 64, wc = (wave & 1) * 64;
  const int fr = lane & 15;
  const int fq = lane >> 4;          // 0..3 -> 8-elem chunk within K-half
  f32x4 acc[4][4] = {};

  for (int k0 = 0; k0 < KP; k0 += 64) {
    // stage A,B tiles (128x64 bf16 = 16 KB each), 4 rounds of 256 lanes
#pragma unroll
    for (int h = 0; h < 4; ++h) {
      int id  = h * 256 + tid;             // chunk id 0..1023
      int row = id >> 3, jc = id & 7;      // physical chunk jc at row
      int sc  = ((jc ^ (row & 7)) << 3);   // logical k-offset (pre-swizzled src)
      int ldsb = (h * 256 + wave * 64) * 16;  // wave-uniform base; HW adds lane*16
      async_cp16(A  + (size_t)(brow + row) * KP + k0 + sc, (char*)As + ldsb);
      async_cp16(Bw + (size_t)(bcol + row) * KP + k0 + sc, (char*)Bs + ldsb);
    }
    __syncthreads();

#pragma unroll
    for (int kk = 0; kk < 2; ++kk) {
      bf16x8 af[4], bf[4];
      const int lc = kk * 4 + fq;          // logical chunk 0..7
#pragma unroll
      for (int i = 0; i < 4; ++i) {
        int r = wr + i * 16 + fr;
        af[i] = *(const bf16x8*)(As + r * 64 + ((lc ^ (r & 7)) << 3));
      }
#pragma unroll
      for (int j = 0; j < 4; ++j) {
        int r = wc + j * 16 + fr;
        bf[j] = *(const bf16x8*)(Bs + r * 64 + ((lc ^ (r & 7)) << 3));
      }
#pragma unroll
      for (int i = 0; i < 4; ++i)
#pragma unroll
        for (int j = 0; j < 4; ++j)
          acc[i][j] = __builtin_amdgcn_mfma_f32_16x16x32_bf16(af[i], bf[j], acc[i][j], 0, 0, 0);
    }
    __syncthreads();
  }

  // epilogue: C/D layout col=lane&15, row=(lane>>4)*4+reg  [m89-verified]
  const int rbase = (lane >> 4) * 4;
#pragma unroll
  for (int j = 0; j < 4; ++j) {
    int col = bcol + wc + j * 16 + fr;   // n = g*256 + o
    int g = col >> 8, o = col & 255;
    float bv = bias[o];
#pragma unroll
    for (int i = 0; i < 4; ++i) {
#pragma unroll
      for (int r = 0; r < 4; ++r) {
        int row = brow + wr + i * 16 + rbase + r;  // row = b*4096 + p
        int bb = row >> 12, p = row & 4095;
        out[(((size_t)(bb * 4 + g) * 4096 + p) << 8) + o] = acc[i][j][r] + bv;
      }
    }
  }
}

// ---------------- kernel 4: out[...,0] = sqrt(sum_{o>=1} y^2 + 1) ----------
__global__ void fixup_k(float* __restrict__ out) {
  int row  = blockIdx.x * 4 + (threadIdx.x >> 6);
  int lane = threadIdx.x & 63;
  const float4 v = *(const float4*)(out + (size_t)row * 256 + lane * 4);
  float s = v.x * v.x + v.y * v.y + v.z * v.z + v.w * v.w;
  if (lane == 0) s -= v.x * v.x;  // exclude channel 0
#pragma unroll
  for (int d = 1; d < 64; d <<= 1) s += __shfl_xor(s, d);
  if (lane == 0) out[(size_t)row * 256] = sqrtf(s + 1.0f);
}

extern "C" void kernel_launch(void* const* d_in, const int* in_sizes, int n_in,
                              void* d_out, int out_size, void* d_ws, size_t ws_size,
                              hipStream_t stream) {
  const float* x    = (const float*)d_in[0];
  const float* W    = (const float*)d_in[1];
  const float* bias = (const float*)d_in[2];
  float* out = (float*)d_out;

  __hip_bfloat16* Wg = (__hip_bfloat16*)d_ws;                                  // 1024*640*2
  __hip_bfloat16* A  = (__hip_bfloat16*)((char*)d_ws + (size_t)N_ * KP * 2);   // 16384*640*2

  prep_w  <<<(N_ * KP + 255) / 256, 256, 0, stream>>>(W, Wg);
  im2col_k<<<256, 512, 0, stream>>>(x, A);
  gemm_k  <<<dim3(M_ / 128, N_ / 128), 256, 0, stream>>>(A, Wg, bias, out);
  fixup_k <<<65536 / 4, 256, 0, stream>>>(out);
}

// Round 3
// 65.644 us; speedup vs baseline: 1.4275x; 1.0533x over previous
//
#include <hip/hip_runtime.h>
#include <hip/hip_bf16.h>

#define CIN 65
#define LIN 577
#define KS  576      // spatial K = 9 steps of 64; t_resc handled as rank-1 epilogue
#define M_  16384    // B * 64*64

typedef __bf16 bf16x8 __attribute__((ext_vector_type(8)));
typedef float  f32x4  __attribute__((ext_vector_type(4)));
typedef unsigned short u16x8 __attribute__((ext_vector_type(8)));

// SIG[r] = flatten(rot90(arange(9).reshape(3,3), r)); SIG[(4-g)&3] = sigma_g^{-1}
__constant__ int SIG[4][9] = {
  {0,1,2,3,4,5,6,7,8},
  {2,5,8,1,4,7,0,3,6},
  {8,7,6,5,4,3,2,1,0},
  {6,3,0,7,4,1,8,5,2}};

// ---- kernel 1: rotate+cast W -> Wg[1024][576] bf16, plus W0c[256] f32 ----
__global__ void prep_w(const float* __restrict__ W, __hip_bfloat16* __restrict__ Wg,
                       float* __restrict__ W0c) {
  int idx = blockIdx.x * 256 + threadIdx.x;
  if (idx < 1024 * KS) {
    int f = idx % KS, n = idx / KS;
    int g = n >> 8, o = n & 255;
    int m = f >> 6, c1 = f & 63;
    int k = SIG[(4 - g) & 3][m];
    Wg[idx] = __float2bfloat16(W[o * LIN + 1 + k * 64 + c1]);
  } else {
    int j = idx - 1024 * KS;
    if (j < 256) W0c[j] = W[j * LIN];
  }
}

// ---- kernel 2: im2col (chunk-major) + t_resc -------------------------------
// A[chunk q][row][8] bf16, q in [0,72): features f = q*8..q*8+7, f = m*64+c1.
// One block per (b,py); x window staged in LDS; writes fully coalesced.
__global__ __launch_bounds__(512) void im2col_k(const float* __restrict__ x,
                                                __hip_bfloat16* __restrict__ A,
                                                float* __restrict__ T) {
  __shared__ float lds[CIN * 3 * 72];   // [c][dy][slot 4+u], u=x-pos in [-1,64]
  const int b = blockIdx.x >> 6, py = blockIdx.x & 63;
  const int tid = threadIdx.x;
  const float* xb = x + (size_t)b * (CIN * 4096);

  for (int i = tid; i < CIN * 3 * 18; i += 512)
    *(f32x4*)&lds[i * 4] = (f32x4){0.f, 0.f, 0.f, 0.f};
  __syncthreads();
  for (int i = tid; i < CIN * 3 * 16; i += 512) {
    int pr = i >> 4, j = i & 15;
    int c = pr / 3, dy = pr - c * 3;
    int hy = py + dy - 1;
    if (hy >= 0 && hy < 64)
      *(f32x4*)&lds[c * 216 + dy * 72 + 4 + j * 4] =
          *(const f32x4*)(xb + c * 4096 + hy * 64 + j * 4);
  }
  __syncthreads();

  const int wave = tid >> 6, px = tid & 63;
  const int rowid = (blockIdx.x << 6) | px;   // b*4096 + py*64 + px
#pragma unroll
  for (int qi = 0; qi < 9; ++qi) {
    int q = wave * 9 + qi;
    int m = q >> 3, cb = (q & 7) * 8;         // chunk = channels cb..cb+7 of tap m
    int dy = m / 3, dx = m - dy * 3;
    const float* src = &lds[(1 + cb) * 216 + dy * 72 + 3 + dx + px];
    u16x8 pk;
#pragma unroll
    for (int e = 0; e < 8; ++e) {
      union { __hip_bfloat16 h; unsigned short u; } cv;
      cv.h = __float2bfloat16(src[e * 216]);
      pk[e] = cv.u;
    }
    *(u16x8*)(A + ((size_t)q * M_ + rowid) * 8) = pk;   // coalesced 16B/lane
  }
  if (wave == 0) {   // t_resc (rotation-invariant), channel 0
    float s = 0.f;
#pragma unroll
    for (int m = 0; m < 9; ++m) {
      float t = fmaxf(lds[(m / 3) * 72 + 3 + (m % 3) + px], 1.f);
      s += t * t;
    }
    T[rowid] = sqrtf(s - 8.f);
  }
}

// ---- kernel 3: GEMM 128x256 tile, BK=64, fused bias + rank-1 + Lorentz norm
__device__ __forceinline__ void async_cp16(const void* g, void* ldsbase) {
  __builtin_amdgcn_global_load_lds(
      (const __attribute__((address_space(1))) void*)g,
      (__attribute__((address_space(3))) void*)ldsbase, 16, 0, 0);
}

__global__ __launch_bounds__(512) void gemm_k(const __hip_bfloat16* __restrict__ A,
                                              const __hip_bfloat16* __restrict__ Bw,
                                              const float* __restrict__ bias,
                                              const float* __restrict__ W0c,
                                              const float* __restrict__ T,
                                              float* __restrict__ out) {
  __shared__ __hip_bfloat16 As[128 * 64];
  __shared__ __hip_bfloat16 Bs[256 * 64];
  __shared__ float Ts[128];
  __shared__ float Ps[128][4];
  const int tid = threadIdx.x;
  const int wave = tid >> 6, lane = tid & 63;
  const int brow = blockIdx.x * 128;
  const int g = blockIdx.y;
  const int wr = (wave >> 2) * 64, wc = (wave & 3) * 64;
  const int fr = lane & 15, fq = lane >> 4;
  if (tid < 128) Ts[tid] = T[brow + tid];
  f32x4 acc[4][4] = {};

  for (int k0 = 0; k0 < KS; k0 += 64) {
    const int kc = k0 >> 3;
    // A tile: 128 rows x 8 chunks; physical chunk jc at row holds logical jc^(row&7)
#pragma unroll
    for (int h = 0; h < 2; ++h) {
      int id = h * 512 + tid, row = id >> 3, jc = id & 7;
      async_cp16(A + ((size_t)(kc + (jc ^ (row & 7))) * M_ + brow + row) * 8,
                 (char*)As + (h * 512 + wave * 64) * 16);
    }
    // B tile: 256 rows x 8 chunks (row-major source)
#pragma unroll
    for (int h = 0; h < 4; ++h) {
      int id = h * 512 + tid, row = id >> 3, jc = id & 7;
      async_cp16(Bw + (size_t)(g * 256 + row) * KS + k0 + ((jc ^ (row & 7)) << 3),
                 (char*)Bs + (h * 512 + wave * 64) * 16);
    }
    __syncthreads();
#pragma unroll
    for (int kk = 0; kk < 2; ++kk) {
      bf16x8 af[4], bf[4];
      const int lc = kk * 4 + fq;
#pragma unroll
      for (int i = 0; i < 4; ++i) {
        int r = wr + i * 16 + fr;
        af[i] = *(const bf16x8*)(As + r * 64 + ((lc ^ (r & 7)) << 3));
      }
#pragma unroll
      for (int j = 0; j < 4; ++j) {
        int r = wc + j * 16 + fr;
        bf[j] = *(const bf16x8*)(Bs + r * 64 + ((lc ^ (r & 7)) << 3));
      }
#pragma unroll
      for (int i = 0; i < 4; ++i)
#pragma unroll
        for (int j = 0; j < 4; ++j)
          acc[i][j] = __builtin_amdgcn_mfma_f32_16x16x32_bf16(af[i], bf[j], acc[i][j], 0, 0, 0);
    }
    __syncthreads();
  }

  // epilogue: y = acc + bias + t*w0; store y (o!=0); accumulate row norms
  const int rbase = fq * 4;
  float rs[4][4], tv[4][4];
#pragma unroll
  for (int i = 0; i < 4; ++i)
#pragma unroll
    for (int r = 0; r < 4; ++r) {
      tv[i][r] = Ts[wr + i * 16 + rbase + r];
      rs[i][r] = 0.f;
    }
#pragma unroll
  for (int j = 0; j < 4; ++j) {
    int o = wc + j * 16 + fr;
    float bv = bias[o];
    float w0 = W0c[o];
    bool nz = (o != 0);
#pragma unroll
    for (int i = 0; i < 4; ++i) {
#pragma unroll
      for (int r = 0; r < 4; ++r) {
        int row = brow + wr + i * 16 + rbase + r;
        int bb = row >> 12, p = row & 4095;
        float y = acc[i][j][r] + bv + tv[i][r] * w0;
        if (nz) {
          rs[i][r] += y * y;
          out[(((size_t)(bb * 4 + g) * 4096 + p) << 8) + o] = y;
        }
      }
    }
  }
  // reduce norm partials across the 16 lanes of each fq group, then cross-wave
#pragma unroll
  for (int i = 0; i < 4; ++i)
#pragma unroll
    for (int r = 0; r < 4; ++r) {
      float s = rs[i][r];
      s += __shfl_xor(s, 1); s += __shfl_xor(s, 2);
      s += __shfl_xor(s, 4); s += __shfl_xor(s, 8);
      if (fr == 0) Ps[wr + i * 16 + rbase + r][wc >> 6] = s;
    }
  __syncthreads();
  if (tid < 128) {
    int row = brow + tid;
    int bb = row >> 12, p = row & 4095;
    float s = Ps[tid][0] + Ps[tid][1] + Ps[tid][2] + Ps[tid][3] + 1.0f;  // +CURV
    out[((size_t)(bb * 4 + g) * 4096 + p) << 8] = sqrtf(s);
  }
}

extern "C" void kernel_launch(void* const* d_in, const int* in_sizes, int n_in,
                              void* d_out, int out_size, void* d_ws, size_t ws_size,
                              hipStream_t stream) {
  const float* x    = (const float*)d_in[0];
  const float* W    = (const float*)d_in[1];
  const float* bias = (const float*)d_in[2];
  float* out = (float*)d_out;

  char* ws = (char*)d_ws;
  __hip_bfloat16* Wg  = (__hip_bfloat16*)ws;                     // 1024*576*2 = 1179648 B
  float*          W0c = (float*)(ws + 1179648);                  // 1024 B
  float*          T   = (float*)(ws + 1180672);                  // 65536 B
  __hip_bfloat16* A   = (__hip_bfloat16*)(ws + 1246208);         // 72*16384*16 B

  prep_w  <<<(1024 * KS + 256 + 255) / 256, 256, 0, stream>>>(W, Wg, W0c);
  im2col_k<<<256, 512, 0, stream>>>(x, A, T);
  gemm_k  <<<dim3(M_ / 128, 4), 512, 0, stream>>>(A, Wg, bias, W0c, T, out);
}

// Round 4
// 51.192 us; speedup vs baseline: 1.8305x; 1.2823x over previous
//
#include <hip/hip_runtime.h>
#include <hip/hip_bf16.h>

#define CIN 65
#define LIN 577
#define NSTEP 18      // K = 576 = 18 steps of 32; t_resc handled as rank-1 epilogue
#define M_  16384

typedef __bf16 bf16x8 __attribute__((ext_vector_type(8)));
typedef float  f32x4  __attribute__((ext_vector_type(4)));
typedef unsigned short u16x8 __attribute__((ext_vector_type(8)));

// SIG[r] = flatten(rot90(arange(9).reshape(3,3), r)); SIG[(4-g)&3] = sigma_g^{-1}
__constant__ int SIG[4][9] = {
  {0,1,2,3,4,5,6,7,8},
  {2,5,8,1,4,7,0,3,6},
  {8,7,6,5,4,3,2,1,0},
  {6,3,0,7,4,1,8,5,2}};

// row-dependent XOR mask for the 4 16B-chunks of a 64B row: 2-way max on b128 reads
__device__ __forceinline__ int swzm(int r) { return (r ^ (r >> 2)) & 3; }

// ---- kernel 1: W -> Wg_t[g][ks][col 256][jc 4][8] bf16 (pre-swizzled) + W0c
__global__ void prep_w(const float* __restrict__ W, __hip_bfloat16* __restrict__ Wg,
                       float* __restrict__ W0c) {
  int idx = blockIdx.x * 256 + threadIdx.x;
  if (idx < 4 * NSTEP * 8192) {
    int e   = idx & 7;
    int jc  = (idx >> 3) & 3;
    int col = (idx >> 5) & 255;
    int ks  = (idx >> 13) % NSTEP;
    int g   = idx / (NSTEP * 8192);
    int lc  = jc ^ swzm(col);
    int m   = ks >> 1;
    int c1  = (ks & 1) * 32 + lc * 8 + e;
    int k   = SIG[(4 - g) & 3][m];
    Wg[idx] = __float2bfloat16(W[col * LIN + 1 + k * 64 + c1]);
  } else {
    int j = idx - 4 * NSTEP * 8192;
    if (j < 256) W0c[j] = W[j * LIN];
  }
}

// ---- kernel 2: im2col -> A_t[rb2 64][ks 18][krow 256][jc 4][8] bf16 + T ----
__global__ __launch_bounds__(512) void im2col_k(const float* __restrict__ x,
                                                __hip_bfloat16* __restrict__ A,
                                                float* __restrict__ T) {
  __shared__ float lds[CIN * 3 * 72];   // [c][dy][slot 4+u], u = x-pos in [-1,64]
  const int b = blockIdx.x >> 6, py = blockIdx.x & 63;
  const int tid = threadIdx.x;
  const float* xb = x + (size_t)b * (CIN * 4096);

  for (int i = tid; i < CIN * 3 * 18; i += 512)
    *(f32x4*)&lds[i * 4] = (f32x4){0.f, 0.f, 0.f, 0.f};
  __syncthreads();
  for (int i = tid; i < CIN * 3 * 16; i += 512) {
    int pr = i >> 4, j = i & 15;
    int c = pr / 3, dy = pr - c * 3;
    int hy = py + dy - 1;
    if (hy >= 0 && hy < 64)
      *(f32x4*)&lds[c * 216 + dy * 72 + 4 + j * 4] =
          *(const f32x4*)(xb + c * 4096 + hy * 64 + j * 4);
  }
  __syncthreads();

  const int wave = tid >> 6, px = tid & 63;
  const int rowid = (blockIdx.x << 6) | px;
  const int rb2 = rowid >> 8, krow = rowid & 255;
#pragma unroll
  for (int qi = 0; qi < 9; ++qi) {
    int q = wave * 9 + qi;                 // 0..71: q = m*8 + cb8
    int m = q >> 3, cb8 = q & 7;
    int ks = m * 2 + (cb8 >> 2);
    int jc = (cb8 & 3) ^ swzm(krow);
    int dy = m / 3, dx = m - dy * 3;
    const float* src = &lds[(1 + cb8 * 8) * 216 + dy * 72 + 3 + dx + px];
    u16x8 pk;
#pragma unroll
    for (int e = 0; e < 8; ++e) {
      union { __hip_bfloat16 h; unsigned short u; } cv;
      cv.h = __float2bfloat16(src[e * 216]);
      pk[e] = cv.u;
    }
    *(u16x8*)(A + ((((size_t)(rb2 * NSTEP + ks) << 8 | krow) << 2 | jc) << 3)) = pk;
  }
  if (wave == 0) {   // t_resc (rotation-invariant)
    float s = 0.f;
#pragma unroll
    for (int m = 0; m < 9; ++m) {
      float t = fmaxf(lds[(m / 3) * 72 + 3 + (m % 3) + px], 1.f);
      s += t * t;
    }
    T[rowid] = sqrtf(s - 8.f);
  }
}

// ---- kernel 3: dbuf 2-phase GEMM 256x256, BK=32, fused bias+rank1+norm ----
__device__ __forceinline__ void async_cp16(const void* g, void* ldsbase) {
  __builtin_amdgcn_global_load_lds(
      (const __attribute__((address_space(1))) void*)g,
      (__attribute__((address_space(3))) void*)ldsbase, 16, 0, 0);
}

__global__ __launch_bounds__(512, 2) void gemm_k(const __hip_bfloat16* __restrict__ A,
                                                 const __hip_bfloat16* __restrict__ Wg,
                                                 const float* __restrict__ bias,
                                                 const float* __restrict__ W0c,
                                                 const float* __restrict__ T,
                                                 float* __restrict__ out) {
  // [A0 16K][A1 16K][B0 16K][B1 16K]; epilogue reuses A0 region for Ps/Tsh
  __shared__ __align__(16) char smem[65536];
  const int tid = threadIdx.x, wave = tid >> 6, lane = tid & 63;
  const int fr = lane & 15, fq = lane >> 4;
  const int rb2 = blockIdx.x, g = blockIdx.y;
  const int brow = rb2 << 8;
  const int wr = (wave >> 2) * 128, wcb = (wave & 3) * 64;
  const __hip_bfloat16* Asrc0 = A  + ((size_t)(rb2 * NSTEP) << 13);
  const __hip_bfloat16* Bsrc0 = Wg + ((size_t)(g   * NSTEP) << 13);
  f32x4 acc[8][4] = {};

  auto STAGE = [&](int buf, int ks) {
#pragma unroll
    for (int h = 0; h < 2; ++h) {
      async_cp16(Asrc0 + (ks << 13) + (h * 512 + tid) * 8,
                 smem + buf * 16384 + (h * 512 + wave * 64) * 16);
      async_cp16(Bsrc0 + (ks << 13) + (h * 512 + tid) * 8,
                 smem + 32768 + buf * 16384 + (h * 512 + wave * 64) * 16);
    }
  };
  auto COMPUTE = [&](int buf) {
    const char* Ab = smem + buf * 16384;
    const char* Bb = smem + 32768 + buf * 16384;
    bf16x8 af[8], bf[4];
#pragma unroll
    for (int i = 0; i < 8; ++i) {
      int r = wr + i * 16 + fr;
      af[i] = *(const bf16x8*)(Ab + r * 64 + ((fq ^ swzm(r)) << 4));
    }
#pragma unroll
    for (int j = 0; j < 4; ++j) {
      int c = wcb + j * 16 + fr;
      bf[j] = *(const bf16x8*)(Bb + c * 64 + ((fq ^ swzm(c)) << 4));
    }
#pragma unroll
    for (int i = 0; i < 8; ++i)
#pragma unroll
      for (int j = 0; j < 4; ++j)
        acc[i][j] = __builtin_amdgcn_mfma_f32_16x16x32_bf16(af[i], bf[j], acc[i][j], 0, 0, 0);
  };

  STAGE(0, 0);
  __syncthreads();
  int cur = 0;
  for (int ks = 0; ks < NSTEP - 1; ++ks) {
    STAGE(cur ^ 1, ks + 1);   // issue next-tile loads first
    COMPUTE(cur);             // ds_read + 32 MFMA hide the staging latency
    __syncthreads();          // vmcnt(0)+lgkmcnt(0)+barrier: next buf ready
    cur ^= 1;
  }
  // tail: buf `cur` (=1) holds ks=17; A0 region is free -> stage T there
  float* Tsh = (float*)(smem + 4096);
  if (tid < 256) Tsh[tid] = T[brow + tid];
  COMPUTE(cur);
  __syncthreads();

  // epilogue: y = acc + bias + t*w0; store y (o!=0); fused Lorentz norm
  float* Ps = (float*)smem;   // [256][4]
  float bo[4], w0v[4]; int oc[4];
#pragma unroll
  for (int j = 0; j < 4; ++j) {
    oc[j]  = wcb + j * 16 + fr;
    bo[j]  = bias[oc[j]];
    w0v[j] = W0c[oc[j]];
  }
#pragma unroll
  for (int i = 0; i < 8; ++i) {
#pragma unroll
    for (int rr = 0; rr < 4; ++rr) {
      int rl = wr + i * 16 + fq * 4 + rr;
      int row = brow + rl;
      size_t obase = ((size_t)(((row >> 12) * 4 + g) * 4096 + (row & 4095)) << 8);
      float tval = Tsh[rl];
      float s = 0.f;
#pragma unroll
      for (int j = 0; j < 4; ++j) {
        float y = acc[i][j][rr] + bo[j] + tval * w0v[j];
        if (oc[j] != 0) { s += y * y; out[obase + oc[j]] = y; }
      }
      s += __shfl_xor(s, 1); s += __shfl_xor(s, 2);
      s += __shfl_xor(s, 4); s += __shfl_xor(s, 8);
      if (fr == 0) Ps[rl * 4 + (wave & 3)] = s;
    }
  }
  __syncthreads();
  if (tid < 256) {
    int row = brow + tid;
    float s = Ps[tid * 4] + Ps[tid * 4 + 1] + Ps[tid * 4 + 2] + Ps[tid * 4 + 3] + 1.0f;
    out[(size_t)(((row >> 12) * 4 + g) * 4096 + (row & 4095)) << 8] = sqrtf(s);
  }
}

extern "C" void kernel_launch(void* const* d_in, const int* in_sizes, int n_in,
                              void* d_out, int out_size, void* d_ws, size_t ws_size,
                              hipStream_t stream) {
  const float* x    = (const float*)d_in[0];
  const float* W    = (const float*)d_in[1];
  const float* bias = (const float*)d_in[2];
  float* out = (float*)d_out;

  char* ws = (char*)d_ws;
  __hip_bfloat16* Wg  = (__hip_bfloat16*)ws;               // 589824*2 = 1179648 B
  float*          W0c = (float*)(ws + 1179648);            // 1024 B
  float*          T   = (float*)(ws + 1180672);            // 65536 B
  __hip_bfloat16* A   = (__hip_bfloat16*)(ws + 1246208);   // 64*18*16384 = 18874368 B

  prep_w  <<<2306, 256, 0, stream>>>(W, Wg, W0c);
  im2col_k<<<256, 512, 0, stream>>>(x, A, T);
  gemm_k  <<<dim3(64, 4), 512, 0, stream>>>(A, Wg, bias, W0c, T, out);
}

// Round 5
// 44.530 us; speedup vs baseline: 2.1044x; 1.1496x over previous
//
#include <hip/hip_runtime.h>
#include <hip/hip_bf16.h>

#define CIN 65
#define LIN 577
#define NSTEP 18      // K = 576 = 18 steps of 32; t_resc is a rank-1 epilogue
#define M_  16384

typedef __bf16 bf16x8 __attribute__((ext_vector_type(8)));
typedef float  f32x4  __attribute__((ext_vector_type(4)));
typedef unsigned short u16x8 __attribute__((ext_vector_type(8)));

// SIG[r] = flatten(rot90(arange(9).reshape(3,3), r)); SIG[(4-g)&3] = sigma_g^{-1}
__constant__ int SIG[4][9] = {
  {0,1,2,3,4,5,6,7,8},
  {2,5,8,1,4,7,0,3,6},
  {8,7,6,5,4,3,2,1,0},
  {6,3,0,7,4,1,8,5,2}};

// XOR mask for the 4 16B-chunks of a 64B LDS row (2-way max bank aliasing = free)
__device__ __forceinline__ int swzm(int r) { return (r ^ (r >> 2)) & 3; }

// ---- kernel 1 (fused): blocks [0,256): im2col -> A[q 72][row 16384][8] + T
//                        blocks [256,400): W -> Wg[g*18+ks][col 256][32] bf16
__global__ __launch_bounds__(512) void prep_k(const float* __restrict__ x,
                                              const float* __restrict__ W,
                                              __hip_bfloat16* __restrict__ A,
                                              __hip_bfloat16* __restrict__ Wg,
                                              float* __restrict__ T) {
  __shared__ float lds[CIN * 3 * 72];   // [c][dy][slot 4+u], u = x-pos in [-1,64]
  const int tid = threadIdx.x;
  if (blockIdx.x >= 256) {              // ---- weight prep branch ----
    int pidx = (blockIdx.x - 256) * 512 + tid;   // 0..73727
    int jc  = pidx & 3;
    int col = (pidx >> 2) & 255;
    int t   = pidx >> 10;               // g*18 + ks
    int ks  = t % NSTEP, g = t / NSTEP;
    int k   = SIG[(4 - g) & 3][ks >> 1];
    const float* src = W + col * LIN + 1 + k * 64 + (ks & 1) * 32 + jc * 8;
    u16x8 pk;
#pragma unroll
    for (int e = 0; e < 8; ++e) {
      union { __hip_bfloat16 h; unsigned short u; } cv;
      cv.h = __float2bfloat16(src[e]);
      pk[e] = cv.u;
    }
    *(u16x8*)(Wg + (size_t)pidx * 8) = pk;
    return;
  }
  // ---- im2col branch ----
  const int b = blockIdx.x >> 6, py = blockIdx.x & 63;
  const float* xb = x + (size_t)b * (CIN * 4096);
  for (int i = tid; i < CIN * 3 * 18; i += 512)
    *(f32x4*)&lds[i * 4] = (f32x4){0.f, 0.f, 0.f, 0.f};
  __syncthreads();
  for (int i = tid; i < CIN * 3 * 16; i += 512) {
    int pr = i >> 4, j = i & 15;
    int c = pr / 3, dy = pr - c * 3;
    int hy = py + dy - 1;
    if (hy >= 0 && hy < 64)
      *(f32x4*)&lds[c * 216 + dy * 72 + 4 + j * 4] =
          *(const f32x4*)(xb + c * 4096 + hy * 64 + j * 4);
  }
  __syncthreads();

  const int wave = tid >> 6, px = tid & 63;
  const int rowid = (blockIdx.x << 6) | px;
#pragma unroll
  for (int qi = 0; qi < 9; ++qi) {
    int q = wave * 9 + qi;               // q = m*8 + cb8 (chunk of 8 channels)
    int m = q >> 3, cb8 = q & 7;
    int dy = m / 3, dx = m - dy * 3;
    const float* src = &lds[(1 + cb8 * 8) * 216 + dy * 72 + 3 + dx + px];
    u16x8 pk;
#pragma unroll
    for (int e = 0; e < 8; ++e) {
      union { __hip_bfloat16 h; unsigned short u; } cv;
      cv.h = __float2bfloat16(src[e * 216]);
      pk[e] = cv.u;
    }
    *(u16x8*)(A + ((size_t)q * M_ + rowid) * 8) = pk;   // dense 16B/lane
  }
  if (wave == 0) {   // t_resc (rotation-invariant)
    float s = 0.f;
#pragma unroll
    for (int m = 0; m < 9; ++m) {
      float t = fmaxf(lds[(m / 3) * 72 + 3 + (m % 3) + px], 1.f);
      s += t * t;
    }
    T[rowid] = sqrtf(s - 8.f);
  }
}

// ---- kernel 2: dbuf GEMM BM=128 BN=256 BK=32, 512 blocks (2/CU), fused epi
__device__ __forceinline__ void async_cp16(const void* g, void* ldsbase) {
  __builtin_amdgcn_global_load_lds(
      (const __attribute__((address_space(1))) void*)g,
      (__attribute__((address_space(3))) void*)ldsbase, 16, 0, 0);
}

__global__ __launch_bounds__(512, 4) void gemm_k(const __hip_bfloat16* __restrict__ A,
                                                 const __hip_bfloat16* __restrict__ Wg,
                                                 const float* __restrict__ W,
                                                 const float* __restrict__ bias,
                                                 const float* __restrict__ T,
                                                 float* __restrict__ out) {
  __shared__ __align__(16) char smem[49152];  // A0 8K | A1 8K | B0 16K | B1 16K
  const int fid = blockIdx.x;
  const int lid = ((fid & 7) << 6) | (fid >> 3);   // XCD-contiguous, bijective
  const int g = lid & 3, rb = lid >> 2;
  const int brow = rb << 7;
  const int tid = threadIdx.x, wave = tid >> 6, lane = tid & 63;
  const int fr = lane & 15, fq = lane >> 4;
  const int wr = (wave >> 2) * 64, wcb = (wave & 3) * 64;

  // gather-swizzle staging constants (LDS dest linear; source permuted)
  const int arow = tid >> 2;                       // A: 1 chunk/thread
  const int alc  = (tid & 3) ^ swzm(arow);
  const int bcol0 = tid >> 2;                      // B: 2 chunks/thread
  const int blc0  = (tid & 3) ^ swzm(bcol0);
  const int bcol1 = 128 + (tid >> 2);
  const int blc1  = (tid & 3) ^ swzm(bcol1);
  f32x4 acc[4][4] = {};

  auto STAGE = [&](int buf, int ks) {
    int qb = (ks >> 1) * 8 + (ks & 1) * 4;         // chunk base for this K-step
    async_cp16(A + (((size_t)(qb + alc) * M_ + brow + arow) << 3),
               smem + buf * 8192 + wave * 1024);
    const __hip_bfloat16* bs = Wg + ((size_t)(g * NSTEP + ks) << 13);
    char* bl = smem + 16384 + buf * 16384 + wave * 1024;
    async_cp16(bs + bcol0 * 32 + blc0 * 8, bl);
    async_cp16(bs + bcol1 * 32 + blc1 * 8, bl + 8192);
  };
  auto COMPUTE = [&](int buf) {
    const char* Ab = smem + buf * 8192;
    const char* Bb = smem + 16384 + buf * 16384;
    bf16x8 af[4], bf[4];
#pragma unroll
    for (int i = 0; i < 4; ++i) {
      int r = wr + i * 16 + fr;
      af[i] = *(const bf16x8*)(Ab + r * 64 + ((fq ^ swzm(r)) << 4));
    }
#pragma unroll
    for (int j = 0; j < 4; ++j) {
      int c = wcb + j * 16 + fr;
      bf[j] = *(const bf16x8*)(Bb + c * 64 + ((fq ^ swzm(c)) << 4));
    }
#pragma unroll
    for (int i = 0; i < 4; ++i)
#pragma unroll
      for (int j = 0; j < 4; ++j)
        acc[i][j] = __builtin_amdgcn_mfma_f32_16x16x32_bf16(af[i], bf[j], acc[i][j], 0, 0, 0);
  };

  STAGE(0, 0);
  __syncthreads();
  int cur = 0;
  for (int ks = 0; ks < NSTEP - 1; ++ks) {
    STAGE(cur ^ 1, ks + 1);
    COMPUTE(cur);
    __syncthreads();
    cur ^= 1;
  }
  // tail: cur==1 -> A1/B1 live; A0 region free for Tsh/Ps
  float* Tsh = (float*)smem;            // 128 floats
  float* Ps  = (float*)(smem + 512);    // [128][4]
  if (tid < 128) Tsh[tid] = T[brow + tid];
  COMPUTE(cur);
  __syncthreads();

  // epilogue: y = acc + bias + t*W[:,0]; store y (o!=0); fused Lorentz norm
  float bo[4], w0v[4]; int oc[4];
#pragma unroll
  for (int j = 0; j < 4; ++j) {
    oc[j]  = wcb + j * 16 + fr;
    bo[j]  = bias[oc[j]];
    w0v[j] = W[oc[j] * LIN];
  }
#pragma unroll
  for (int i = 0; i < 4; ++i) {
#pragma unroll
    for (int rr = 0; rr < 4; ++rr) {
      int rl = wr + i * 16 + fq * 4 + rr;
      int row = brow + rl;
      size_t obase = ((size_t)(((row >> 12) * 4 + g) * 4096 + (row & 4095)) << 8);
      float tval = Tsh[rl];
      float s = 0.f;
#pragma unroll
      for (int j = 0; j < 4; ++j) {
        float y = acc[i][j][rr] + bo[j] + tval * w0v[j];
        if (oc[j] != 0) { s += y * y; out[obase + oc[j]] = y; }
      }
      s += __shfl_xor(s, 1); s += __shfl_xor(s, 2);
      s += __shfl_xor(s, 4); s += __shfl_xor(s, 8);
      if (fr == 0) Ps[rl * 4 + (wave & 3)] = s;
    }
  }
  __syncthreads();
  if (tid < 128) {
    int row = brow + tid;
    float s = Ps[tid * 4] + Ps[tid * 4 + 1] + Ps[tid * 4 + 2] + Ps[tid * 4 + 3] + 1.0f;
    out[(size_t)(((row >> 12) * 4 + g) * 4096 + (row & 4095)) << 8] = sqrtf(s);
  }
}

extern "C" void kernel_launch(void* const* d_in, const int* in_sizes, int n_in,
                              void* d_out, int out_size, void* d_ws, size_t ws_size,
                              hipStream_t stream) {
  const float* x    = (const float*)d_in[0];
  const float* W    = (const float*)d_in[1];
  const float* bias = (const float*)d_in[2];
  float* out = (float*)d_out;

  char* ws = (char*)d_ws;
  __hip_bfloat16* Wg = (__hip_bfloat16*)ws;                 // 73728*8*2 = 1179648 B
  float*          T  = (float*)(ws + 1179648);              // 65536 B
  __hip_bfloat16* A  = (__hip_bfloat16*)(ws + 1245184);     // 72*16384*8*2 = 18874368 B

  prep_k<<<400, 512, 0, stream>>>(x, W, A, Wg, T);
  gemm_k<<<512, 512, 0, stream>>>(A, Wg, W, bias, T, out);
}

// Round 6
// 43.477 us; speedup vs baseline: 2.1553x; 1.0242x over previous
//
#include <hip/hip_runtime.h>
#include <hip/hip_bf16.h>

#define CIN 65
#define LIN 577
#define NSTEP 18      // K = 576 = 18 steps of 32; t_resc is a rank-1 epilogue
#define M_  16384

typedef __bf16 bf16x8 __attribute__((ext_vector_type(8)));
typedef float  f32x4  __attribute__((ext_vector_type(4)));
typedef unsigned short u16x8 __attribute__((ext_vector_type(8)));

// SIG[r] = flatten(rot90(arange(9).reshape(3,3), r)); SIG[(4-g)&3] = sigma_g^{-1}
__constant__ int SIG[4][9] = {
  {0,1,2,3,4,5,6,7,8},
  {2,5,8,1,4,7,0,3,6},
  {8,7,6,5,4,3,2,1,0},
  {6,3,0,7,4,1,8,5,2}};

// XOR mask for the 4 16B-chunks of a 64B LDS row (2-way max bank aliasing = free)
__device__ __forceinline__ int swzm(int r) { return (r ^ (r >> 2)) & 3; }

// ---- kernel 1 (fused): blocks [0,256): im2col -> A[q 72][row 16384][8] + T
//                        blocks [256,400): W -> Wg[g*18+ks][col 256][32] bf16
__global__ __launch_bounds__(512) void prep_k(const float* __restrict__ x,
                                              const float* __restrict__ W,
                                              __hip_bfloat16* __restrict__ A,
                                              __hip_bfloat16* __restrict__ Wg,
                                              float* __restrict__ T) {
  __shared__ float lds[CIN * 3 * 72];   // [c][dy][slot 4+u], u = x-pos in [-1,64]
  const int tid = threadIdx.x;
  if (blockIdx.x >= 256) {              // ---- weight prep branch ----
    int pidx = (blockIdx.x - 256) * 512 + tid;   // 0..73727
    int jc  = pidx & 3;
    int col = (pidx >> 2) & 255;
    int t   = pidx >> 10;               // g*18 + ks
    int ks  = t % NSTEP, g = t / NSTEP;
    int k   = SIG[(4 - g) & 3][ks >> 1];
    const float* src = W + col * LIN + 1 + k * 64 + (ks & 1) * 32 + jc * 8;
    u16x8 pk;
#pragma unroll
    for (int e = 0; e < 8; ++e) {
      union { __hip_bfloat16 h; unsigned short u; } cv;
      cv.h = __float2bfloat16(src[e]);
      pk[e] = cv.u;
    }
    *(u16x8*)(Wg + (size_t)pidx * 8) = pk;
    return;
  }
  // ---- im2col branch ----
  const int b = blockIdx.x >> 6, py = blockIdx.x & 63;
  const float* xb = x + (size_t)b * (CIN * 4096);
  for (int i = tid; i < CIN * 3 * 18; i += 512)
    *(f32x4*)&lds[i * 4] = (f32x4){0.f, 0.f, 0.f, 0.f};
  __syncthreads();
  for (int i = tid; i < CIN * 3 * 16; i += 512) {
    int pr = i >> 4, j = i & 15;
    int c = pr / 3, dy = pr - c * 3;
    int hy = py + dy - 1;
    if (hy >= 0 && hy < 64)
      *(f32x4*)&lds[c * 216 + dy * 72 + 4 + j * 4] =
          *(const f32x4*)(xb + c * 4096 + hy * 64 + j * 4);
  }
  __syncthreads();

  const int wave = tid >> 6, px = tid & 63;
  const int rowid = (blockIdx.x << 6) | px;
#pragma unroll
  for (int qi = 0; qi < 9; ++qi) {
    int q = wave * 9 + qi;               // q = m*8 + cb8 (chunk of 8 channels)
    int m = q >> 3, cb8 = q & 7;
    int dy = m / 3, dx = m - dy * 3;
    const float* src = &lds[(1 + cb8 * 8) * 216 + dy * 72 + 3 + dx + px];
    u16x8 pk;
#pragma unroll
    for (int e = 0; e < 8; ++e) {
      union { __hip_bfloat16 h; unsigned short u; } cv;
      cv.h = __float2bfloat16(src[e * 216]);
      pk[e] = cv.u;
    }
    *(u16x8*)(A + ((size_t)q * M_ + rowid) * 8) = pk;   // dense 16B/lane
  }
  if (wave == 0) {   // t_resc (rotation-invariant)
    float s = 0.f;
#pragma unroll
    for (int m = 0; m < 9; ++m) {
      float t = fmaxf(lds[(m / 3) * 72 + 3 + (m % 3) + px], 1.f);
      s += t * t;
    }
    T[rowid] = sqrtf(s - 8.f);
  }
}

// ---- kernel 2: 3-deep pipelined GEMM BM=128 BN=256 BK=32, counted vmcnt ---
__device__ __forceinline__ void async_cp16(const void* g, void* ldsbase) {
  __builtin_amdgcn_global_load_lds(
      (const __attribute__((address_space(1))) void*)g,
      (__attribute__((address_space(3))) void*)ldsbase, 16, 0, 0);
}

__global__ __launch_bounds__(512, 4) void gemm_k(const __hip_bfloat16* __restrict__ A,
                                                 const __hip_bfloat16* __restrict__ Wg,
                                                 const float* __restrict__ W,
                                                 const float* __restrict__ bias,
                                                 const float* __restrict__ T,
                                                 float* __restrict__ out) {
  // A bufs: 0/8K/16K (8 KB each). B bufs: 24K/40K/56K (16 KB each). 72 KB total.
  __shared__ __align__(16) char smem[73728];
  const int fid = blockIdx.x;
  const int lid = ((fid & 7) << 6) | (fid >> 3);   // XCD-contiguous, bijective
  const int g = lid & 3, rb = lid >> 2;
  const int brow = rb << 7;
  const int tid = threadIdx.x, wave = tid >> 6, lane = tid & 63;
  const int fr = lane & 15, fq = lane >> 4;
  const int wr = (wave >> 2) * 64, wcb = (wave & 3) * 64;

  // gather-swizzle staging constants (LDS dest linear; global source permuted)
  const int arow = tid >> 2;                       // A: 1 chunk/thread
  const int alc  = (tid & 3) ^ swzm(arow);
  const int bcol0 = tid >> 2;                      // B: 2 chunks/thread
  const int blc0  = (tid & 3) ^ swzm(bcol0);
  const int bcol1 = 128 + (tid >> 2);
  const int blc1  = (tid & 3) ^ swzm(bcol1);
  f32x4 acc[4][4] = {};

  auto STAGE = [&](char* pa, char* pb, int ks) {
    int qb = (ks >> 1) * 8 + (ks & 1) * 4;         // chunk base for this K-step
    async_cp16(A + (((size_t)(qb + alc) * M_ + brow + arow) << 3), pa + wave * 1024);
    const __hip_bfloat16* bs = Wg + ((size_t)(g * NSTEP + ks) << 13);
    async_cp16(bs + bcol0 * 32 + blc0 * 8, pb + wave * 1024);
    async_cp16(bs + bcol1 * 32 + blc1 * 8, pb + wave * 1024 + 8192);
  };
  auto COMPUTE = [&](const char* Ab, const char* Bb) {
    bf16x8 af[4], bf[4];
#pragma unroll
    for (int i = 0; i < 4; ++i) {
      int r = wr + i * 16 + fr;
      af[i] = *(const bf16x8*)(Ab + r * 64 + ((fq ^ swzm(r)) << 4));
    }
#pragma unroll
    for (int j = 0; j < 4; ++j) {
      int c = wcb + j * 16 + fr;
      bf[j] = *(const bf16x8*)(Bb + c * 64 + ((fq ^ swzm(c)) << 4));
    }
    __builtin_amdgcn_s_setprio(1);
#pragma unroll
    for (int i = 0; i < 4; ++i)
#pragma unroll
      for (int j = 0; j < 4; ++j)
        acc[i][j] = __builtin_amdgcn_mfma_f32_16x16x32_bf16(af[i], bf[j], acc[i][j], 0, 0, 0);
    __builtin_amdgcn_s_setprio(0);
  };

  float* Tsh = (float*)smem;            // aliases A-phys0, dead after ks=15
  char *cA = smem,         *nA = smem + 8192,  *tA = smem + 16384;
  char *cB = smem + 24576, *nB = smem + 40960, *tB = smem + 57344;
  STAGE(cA, cB, 0);
  STAGE(nA, nB, 1);
  for (int ks = 0; ks < NSTEP; ++ks) {
    if (ks < NSTEP - 1) {
      asm volatile("s_waitcnt vmcnt(3)" ::: "memory");  // oldest stage landed; next stays in flight
    } else {
      asm volatile("s_waitcnt vmcnt(0)" ::: "memory");
    }
    __builtin_amdgcn_s_barrier();
    if (ks + 2 < NSTEP) STAGE(tA, tB, ks + 2);
    if (ks == NSTEP - 1 && tid < 128) Tsh[tid] = T[brow + tid];  // phys0 free (ks%3==2)
    COMPUTE(cA, cB);
    char* r = cA; cA = nA; nA = tA; tA = r;
    r = cB; cB = nB; nB = tB; tB = r;
  }
  __syncthreads();   // all compute + Tsh staging done; smem reusable

  // epilogue: y = acc + bias + t*W[:,0]; store y (o!=0); fused Lorentz norm
  float* Ps = (float*)(smem + 512);    // [128][4]
  float bo[4], w0v[4]; int oc[4];
#pragma unroll
  for (int j = 0; j < 4; ++j) {
    oc[j]  = wcb + j * 16 + fr;
    bo[j]  = bias[oc[j]];
    w0v[j] = W[oc[j] * LIN];
  }
#pragma unroll
  for (int i = 0; i < 4; ++i) {
#pragma unroll
    for (int rr = 0; rr < 4; ++rr) {
      int rl = wr + i * 16 + fq * 4 + rr;
      int row = brow + rl;
      size_t obase = ((size_t)(((row >> 12) * 4 + g) * 4096 + (row & 4095)) << 8);
      float tval = Tsh[rl];
      float s = 0.f;
#pragma unroll
      for (int j = 0; j < 4; ++j) {
        float y = acc[i][j][rr] + bo[j] + tval * w0v[j];
        if (oc[j] != 0) { s += y * y; out[obase + oc[j]] = y; }
      }
      s += __shfl_xor(s, 1); s += __shfl_xor(s, 2);
      s += __shfl_xor(s, 4); s += __shfl_xor(s, 8);
      if (fr == 0) Ps[rl * 4 + (wave & 3)] = s;
    }
  }
  __syncthreads();
  if (tid < 128) {
    int row = brow + tid;
    float s = Ps[tid * 4] + Ps[tid * 4 + 1] + Ps[tid * 4 + 2] + Ps[tid * 4 + 3] + 1.0f;
    out[(size_t)(((row >> 12) * 4 + g) * 4096 + (row & 4095)) << 8] = sqrtf(s);
  }
}

extern "C" void kernel_launch(void* const* d_in, const int* in_sizes, int n_in,
                              void* d_out, int out_size, void* d_ws, size_t ws_size,
                              hipStream_t stream) {
  const float* x    = (const float*)d_in[0];
  const float* W    = (const float*)d_in[1];
  const float* bias = (const float*)d_in[2];
  float* out = (float*)d_out;

  char* ws = (char*)d_ws;
  __hip_bfloat16* Wg = (__hip_bfloat16*)ws;                 // 73728*8*2 = 1179648 B
  float*          T  = (float*)(ws + 1179648);              // 65536 B
  __hip_bfloat16* A  = (__hip_bfloat16*)(ws + 1245184);     // 72*16384*8*2 = 18874368 B

  prep_k<<<400, 512, 0, stream>>>(x, W, A, Wg, T);
  gemm_k<<<512, 512, 0, stream>>>(A, Wg, W, bias, T, out);
}